// Round 1
// baseline (696.015 us; speedup 1.0000x reference)
//
#include <hip/hip_runtime.h>
#include <cstdint>

constexpr int H  = 16;
constexpr int D  = 64;
constexpr int DM = 1024;
constexpr int B  = 2;
constexpr int SL = 1024;
constexpr int CL = 512;
constexpr int KL = SL + CL;   // 1536
constexpr int SPAD = KL + 8;  // padded score row (fp32) to break LDS bank conflicts

typedef short bf16x8  __attribute__((ext_vector_type(8)));
typedef float f32x4   __attribute__((ext_vector_type(4)));
typedef short short4v __attribute__((ext_vector_type(4)));

__device__ __forceinline__ short f2b(float f) {
    uint32_t u = __float_as_uint(f);
    u = (u + 0x7fffu + ((u >> 16) & 1u)) >> 16;   // RNE fp32 -> bf16
    return (short)u;
}

__device__ __forceinline__ bf16x8 cvt8(const float* p) {
    const float4* q = reinterpret_cast<const float4*>(p);
    float4 a = q[0], b = q[1];
    bf16x8 r;
    r[0]=f2b(a.x); r[1]=f2b(a.y); r[2]=f2b(a.z); r[3]=f2b(a.w);
    r[4]=f2b(b.x); r[5]=f2b(b.y); r[6]=f2b(b.z); r[7]=f2b(b.w);
    return r;
}

__device__ __forceinline__ bf16x8 ld8(const unsigned short* p) {
    return *reinterpret_cast<const bf16x8*>(p);
}

// C[M,1024] = A[M,1024] @ W[1024,1024]^T + bias, then scaled.
// MODE 0: write bf16 to [b, h, OUTLEN, 64] at row offset ROWOFF
// MODE 1: write bf16 V^T to [b, h, 64, KL] at col offset ROWOFF
// MODE 2: write fp32 row-major [M, 1024]
template<int MODE, int A_BF16, int RPB_SHIFT, int OUTLEN, int ROWOFF>
__global__ __launch_bounds__(256)
void proj_gemm(const void* __restrict__ Aptr, const float* __restrict__ W,
               const float* __restrict__ bias, void* __restrict__ outp, float scale)
{
    const int l   = threadIdx.x & 63;
    const int wid = threadIdx.x >> 6;
    const int wr  = wid >> 1, wc = wid & 1;
    const int rowbase = blockIdx.y * 64 + wr * 32;
    const int colbase = blockIdx.x * 64 + wc * 32;
    const int lr = l & 15, lk = (l >> 4) * 8;

    f32x4 acc[2][2] = {};
    for (int k0 = 0; k0 < DM; k0 += 32) {
        bf16x8 af[2], wf[2];
        #pragma unroll
        for (int mb = 0; mb < 2; ++mb) {
            int row = rowbase + mb * 16 + lr;
            if (A_BF16) af[mb] = ld8((const unsigned short*)Aptr + (size_t)row * DM + k0 + lk);
            else        af[mb] = cvt8((const float*)Aptr + (size_t)row * DM + k0 + lk);
        }
        #pragma unroll
        for (int nb = 0; nb < 2; ++nb) {
            int n = colbase + nb * 16 + lr;
            wf[nb] = cvt8(W + (size_t)n * DM + k0 + lk);
        }
        #pragma unroll
        for (int mb = 0; mb < 2; ++mb)
            #pragma unroll
            for (int nb = 0; nb < 2; ++nb)
                acc[mb][nb] = __builtin_amdgcn_mfma_f32_16x16x32_bf16(af[mb], wf[nb], acc[mb][nb], 0, 0, 0);
    }

    #pragma unroll
    for (int mb = 0; mb < 2; ++mb) {
        #pragma unroll
        for (int nb = 0; nb < 2; ++nb) {
            int n = colbase + nb * 16 + lr;          // C/D col = lane&15
            float bi = bias[n];
            if (MODE == 1) {
                // rows for reg 0..3 are consecutive -> pack 4 bf16 (8B) store
                int m0 = rowbase + mb * 16 + (l >> 4) * 4;
                int bb = m0 >> RPB_SHIFT;
                int s0 = m0 & ((1 << RPB_SHIFT) - 1);
                int hh = n >> 6, dd = n & 63;
                unsigned short* o = (unsigned short*)outp +
                    ((size_t)(bb * H + hh) * D + dd) * KL + ROWOFF + s0;
                short4v pk;
                #pragma unroll
                for (int r = 0; r < 4; ++r) pk[r] = f2b((acc[mb][nb][r] + bi) * scale);
                *reinterpret_cast<short4v*>(o) = pk;
            } else {
                #pragma unroll
                for (int r = 0; r < 4; ++r) {
                    int m = rowbase + mb * 16 + (l >> 4) * 4 + r;  // C/D row
                    float v = (acc[mb][nb][r] + bi) * scale;
                    if (MODE == 0) {
                        int bb = m >> RPB_SHIFT;
                        int s  = m & ((1 << RPB_SHIFT) - 1);
                        int hh = n >> 6, dd = n & 63;
                        ((unsigned short*)outp)[((size_t)(bb * H + hh) * OUTLEN + ROWOFF + s) * D + dd]
                            = (unsigned short)f2b(v);
                    } else {
                        ((float*)outp)[(size_t)m * DM + n] = v;
                    }
                }
            }
        }
    }
}

// One block per (b, h, 16-row q tile). 256 threads = 4 waves.
__global__ __launch_bounds__(256)
void attn_kernel(const unsigned short* __restrict__ q_ws,
                 const unsigned short* __restrict__ k_ws,
                 const unsigned short* __restrict__ vT_ws,
                 const int* __restrict__ self_mask,
                 const int* __restrict__ ctx_mask,
                 const float* __restrict__ ctx_bias,
                 float* __restrict__ attn_out,
                 float* __restrict__ top_out,
                 unsigned short* __restrict__ ctx_ws)
{
    __shared__ float s_scores[16 * SPAD];   // 98,816 B
    __shared__ float s_part[4 * 16 * 64];   // 16,384 B
    __shared__ float s_rden[16];

    const int bid = blockIdx.x;
    const int qt  = bid & 63;        // q tile (SL/16 = 64)
    const int bh  = bid >> 6;        // b*H + h
    const int b   = bh >> 4;
    const int h   = bh & 15;
    const int l   = threadIdx.x & 63;
    const int wid = threadIdx.x >> 6;
    const int lr  = l & 15;
    const int lkg = l >> 4;

    const unsigned short* qb = q_ws + (size_t)bh * SL * D + (size_t)qt * 16 * D;
    const unsigned short* kb = k_ws + (size_t)bh * KL * D;
    const unsigned short* vb = vT_ws + (size_t)bh * D * KL;

    // Q fragments (A operand): lane holds Q[l&15][(l>>4)*8 + i], two k-steps
    bf16x8 aq0 = ld8(qb + lr * D + lkg * 8);
    bf16x8 aq1 = ld8(qb + lr * D + 32 + lkg * 8);

    // scores: each wave owns 24 of the 96 col-fragments
    for (int jj = 0; jj < 24; ++jj) {
        int j = wid * 24 + jj;
        int kp = j * 16 + lr;
        bf16x8 bk0 = ld8(kb + (size_t)kp * D + lkg * 8);
        bf16x8 bk1 = ld8(kb + (size_t)kp * D + 32 + lkg * 8);
        f32x4 c = {};
        c = __builtin_amdgcn_mfma_f32_16x16x32_bf16(aq0, bk0, c, 0, 0, 0);
        c = __builtin_amdgcn_mfma_f32_16x16x32_bf16(aq1, bk1, c, 0, 0, 0);
        #pragma unroll
        for (int r = 0; r < 4; ++r)
            s_scores[(lkg * 4 + r) * SPAD + j * 16 + lr] = c[r];
    }
    __syncthreads();

    // masked softmax: row = tid>>4, 16 threads per row striding cols
    {
        const int rr = threadIdx.x >> 4;
        const int c0 = threadIdx.x & 15;
        const int qg = qt * 16 + rr;
        const float cb = ctx_bias[0];
        const int* smrow = self_mask + ((size_t)b * SL + qg) * SL;
        const int* cmrow = ctx_mask + (size_t)b * CL;

        float mx = -3.0e38f;
        for (int j = 0; j < KL / 16; ++j) {
            int c = c0 + j * 16;
            float s = s_scores[rr * SPAD + c];
            if (c < SL) { if (smrow[c] != 0) s = -1e30f; }
            else        { s += cb; if (cmrow[c - SL] != 0) s = -1e30f; }
            s_scores[rr * SPAD + c] = s;
            mx = fmaxf(mx, s);
        }
        #pragma unroll
        for (int o = 1; o < 16; o <<= 1) mx = fmaxf(mx, __shfl_xor(mx, o));

        float sum = 0.f, csum = 0.f;
        for (int j = 0; j < KL / 16; ++j) {
            int c = c0 + j * 16;
            float e = __expf(s_scores[rr * SPAD + c] - mx);
            s_scores[rr * SPAD + c] = e;
            sum += e;
            if (c >= SL) csum += e;
        }
        #pragma unroll
        for (int o = 1; o < 16; o <<= 1) { sum += __shfl_xor(sum, o); csum += __shfl_xor(csum, o); }
        float rden = 1.0f / sum;
        float rcs  = 1.0f / csum;
        if (c0 == 0) s_rden[rr] = rden;

        float* arow = attn_out + ((size_t)bh * SL + qg) * KL;
        float* trow = top_out + ((size_t)b * SL + qg) * CL;
        for (int j = 0; j < KL / 16; ++j) {
            int c = c0 + j * 16;
            float e = s_scores[rr * SPAD + c];
            arow[c] = e * rden;
            if (h == 0 && c >= SL) trow[c - SL] = e * rcs;
        }
    }
    __syncthreads();

    // PV on unnormalized e; wave w owns K slice [w*384, w*384+384)
    f32x4 accv[4] = {};
    for (int ks = 0; ks < 12; ++ks) {
        int k0 = wid * 384 + ks * 32;
        const float* prow = s_scores + lr * SPAD + k0 + lkg * 8;
        float4 p0 = *reinterpret_cast<const float4*>(prow);
        float4 p1 = *reinterpret_cast<const float4*>(prow + 4);
        bf16x8 ap;
        ap[0]=f2b(p0.x); ap[1]=f2b(p0.y); ap[2]=f2b(p0.z); ap[3]=f2b(p0.w);
        ap[4]=f2b(p1.x); ap[5]=f2b(p1.y); ap[6]=f2b(p1.z); ap[7]=f2b(p1.w);
        #pragma unroll
        for (int df = 0; df < 4; ++df) {
            bf16x8 bv = ld8(vb + (size_t)(df * 16 + lr) * KL + k0 + lkg * 8);
            accv[df] = __builtin_amdgcn_mfma_f32_16x16x32_bf16(ap, bv, accv[df], 0, 0, 0);
        }
    }
    #pragma unroll
    for (int df = 0; df < 4; ++df)
        #pragma unroll
        for (int r = 0; r < 4; ++r)
            s_part[wid * 1024 + (lkg * 4 + r) * 64 + df * 16 + lr] = accv[df][r];
    __syncthreads();

    for (int i = threadIdx.x; i < 1024; i += 256) {
        int s = i >> 6, dd = i & 63;
        float v = s_part[i] + s_part[1024 + i] + s_part[2048 + i] + s_part[3072 + i];
        v *= s_rden[s];
        ctx_ws[((size_t)b * SL + (size_t)qt * 16 + s) * DM + h * D + dd] = (unsigned short)f2b(v);
    }
}

extern "C" void kernel_launch(void* const* d_in, const int* in_sizes, int n_in,
                              void* d_out, int out_size, void* d_ws, size_t ws_size,
                              hipStream_t stream)
{
    const float* self_kvq = (const float*)d_in[0];
    const float* ctx_kv   = (const float*)d_in[1];
    const int*   self_mask= (const int*)d_in[2];
    const int*   ctx_mask = (const int*)d_in[3];
    const float* Wq  = (const float*)d_in[4];
    const float* bq  = (const float*)d_in[5];
    const float* Wks = (const float*)d_in[6];
    const float* bks = (const float*)d_in[7];
    const float* Wvs = (const float*)d_in[8];
    const float* bvs = (const float*)d_in[9];
    const float* Wkc = (const float*)d_in[10];
    const float* bkc = (const float*)d_in[11];
    const float* Wvc = (const float*)d_in[12];
    const float* bvc = (const float*)d_in[13];
    const float* ctx_bias = (const float*)d_in[14];
    const float* Wo  = (const float*)d_in[15];
    const float* bo  = (const float*)d_in[16];

    float* out0     = (float*)d_out;                       // (B, SL, DM)
    float* out_top  = out0 + (size_t)B * SL * DM;          // (B, SL, CL)
    float* out_attn = out_top + (size_t)B * SL * CL;       // (B, H, SL, KL)

    unsigned short* q_ws   = (unsigned short*)d_ws;                 // [B,H,SL,64]
    unsigned short* k_ws   = q_ws  + (size_t)B * H * SL * D;        // [B,H,KL,64]
    unsigned short* vT_ws  = k_ws  + (size_t)B * H * KL * D;        // [B,H,64,KL]
    unsigned short* ctx_ws = vT_ws + (size_t)B * H * KL * D;        // [B*SL, DM]

    // projections (N = DM = 1024 -> grid.x = 16)
    proj_gemm<0,0,10,SL,0 ><<<dim3(16,32),256,0,stream>>>(self_kvq, Wq,  bq,  q_ws,  0.125f);
    proj_gemm<0,0,10,KL,0 ><<<dim3(16,32),256,0,stream>>>(self_kvq, Wks, bks, k_ws,  1.0f);
    proj_gemm<0,0, 9,KL,SL><<<dim3(16,16),256,0,stream>>>(ctx_kv,   Wkc, bkc, k_ws,  1.0f);
    proj_gemm<1,0,10, 0,0 ><<<dim3(16,32),256,0,stream>>>(self_kvq, Wvs, bvs, vT_ws, 1.0f);
    proj_gemm<1,0, 9, 0,SL><<<dim3(16,16),256,0,stream>>>(ctx_kv,   Wvc, bvc, vT_ws, 1.0f);

    attn_kernel<<<dim3(B * H * (SL / 16)),256,0,stream>>>(q_ws, k_ws, vT_ws,
        self_mask, ctx_mask, ctx_bias, out_attn, out_top, ctx_ws);

    proj_gemm<2,1,10, 0,0 ><<<dim3(16,32),256,0,stream>>>(ctx_ws, Wo, bo, out0, 1.0f);
}

// Round 2
// 445.741 us; speedup vs baseline: 1.5615x; 1.5615x over previous
//
#include <hip/hip_runtime.h>
#include <cstdint>

constexpr int H  = 16;
constexpr int D  = 64;
constexpr int DM = 1024;
constexpr int B  = 2;
constexpr int SL = 1024;
constexpr int CL = 512;
constexpr int KL = SL + CL;   // 1536
constexpr int SPAD = KL + 4;  // 1540: mod 32 = 4 -> score-store 2-way, PV reads 8 bank-starts
constexpr size_t M1 = 1u << 20;

typedef short bf16x8  __attribute__((ext_vector_type(8)));
typedef float f32x4   __attribute__((ext_vector_type(4)));
typedef short short4v __attribute__((ext_vector_type(4)));

__device__ __forceinline__ short f2b(float f) {
    uint32_t u = __float_as_uint(f);
    u = (u + 0x7fffu + ((u >> 16) & 1u)) >> 16;   // RNE fp32 -> bf16
    return (short)u;
}

__device__ __forceinline__ bf16x8 ld8(const unsigned short* p) {
    return *reinterpret_cast<const bf16x8*>(p);
}

__device__ __forceinline__ void async16(const void* g, void* l) {
    __builtin_amdgcn_global_load_lds(
        (const __attribute__((address_space(1))) void*)g,
        (__attribute__((address_space(3))) void*)l,
        16, 0, 0);
}

// ---------------- fp32 -> bf16 bulk convert --------------------------------
// dst layout (1M-element units): [0,2) self_kvq, [2,3) ctx_kv, [3,4) Wq,
// [4,5) Wks, [5,6) Wvs, [6,7) Wkc, [7,8) Wvc, [8,9) Wo
struct ConvSrc { const float* p[8]; };

__global__ __launch_bounds__(256)
void convert_kernel(ConvSrc srcs, unsigned short* __restrict__ dst)
{
    size_t i8 = (size_t)blockIdx.x * 256 + threadIdx.x;   // 8-elem chunk
    size_t e  = i8 * 8;                                   // < 9M
    int u = (int)(e >> 20);
    const float* s; size_t off;
    if (u < 2) { s = srcs.p[0]; off = e; }
    else       { s = srcs.p[u - 1]; off = e - ((size_t)u << 20); }
    float4 a = *reinterpret_cast<const float4*>(s + off);
    float4 b = *reinterpret_cast<const float4*>(s + off + 4);
    bf16x8 r;
    r[0]=f2b(a.x); r[1]=f2b(a.y); r[2]=f2b(a.z); r[3]=f2b(a.w);
    r[4]=f2b(b.x); r[5]=f2b(b.y); r[6]=f2b(b.z); r[7]=f2b(b.w);
    *reinterpret_cast<bf16x8*>(dst + e) = r;
}

// ---------------- 128x128-tile LDS-staged bf16 GEMM ------------------------
// C[M,1024] = A[M,1024] @ W[1024,1024]^T + bias, scaled.
// MODE 0: bf16 -> [b, h, OUTLEN, 64] at row offset ROWOFF
// MODE 1: bf16 V^T -> [b, h, 64, KL] at col offset ROWOFF
// MODE 2: fp32 row-major [M, 1024]
template<int MODE, int RPB_SHIFT, int OUTLEN, int ROWOFF>
__device__ __forceinline__ void gemm128_body(
    const unsigned short* __restrict__ A,
    const unsigned short* __restrict__ W,
    const float* __restrict__ bias,
    void* __restrict__ outp, float scale,
    unsigned short* sA, unsigned short* sB)
{
    const int t   = threadIdx.x;
    const int l   = t & 63;
    const int wid = t >> 6;
    const int wr  = wid >> 1, wc = wid & 1;
    const int lr  = l & 15,  lg = l >> 4;
    const int mbase = blockIdx.y * 128;
    const int nbase = blockIdx.x * 128;

    f32x4 acc[4][4] = {};
    for (int k0 = 0; k0 < DM; k0 += 32) {
        #pragma unroll
        for (int i = 0; i < 2; ++i) {
            int c   = t + 256 * i;          // 16B chunk id, 0..511
            int row = c >> 2, kc = (c & 3) * 8;
            async16(A + (size_t)(mbase + row) * DM + k0 + kc, sA + c * 8);
            async16(W + (size_t)(nbase + row) * DM + k0 + kc, sB + c * 8);
        }
        __syncthreads();                     // vmcnt(0) drained by compiler
        bf16x8 af[4], bfr[4];
        #pragma unroll
        for (int i = 0; i < 4; ++i) {
            af[i]  = ld8(sA + (wr * 64 + i * 16 + lr) * 32 + lg * 8);
            bfr[i] = ld8(sB + (wc * 64 + i * 16 + lr) * 32 + lg * 8);
        }
        #pragma unroll
        for (int i = 0; i < 4; ++i)
            #pragma unroll
            for (int j = 0; j < 4; ++j)
                acc[i][j] = __builtin_amdgcn_mfma_f32_16x16x32_bf16(af[i], bfr[j], acc[i][j], 0, 0, 0);
        __syncthreads();                     // protect LDS before next stage
    }

    #pragma unroll
    for (int mi = 0; mi < 4; ++mi) {
        #pragma unroll
        for (int nj = 0; nj < 4; ++nj) {
            int n = nbase + wc * 64 + nj * 16 + lr;      // C/D col = lane&15
            float bi = bias[n];
            if (MODE == 1) {
                int m0 = mbase + wr * 64 + mi * 16 + lg * 4;
                int bb = m0 >> RPB_SHIFT;
                int s0 = m0 & ((1 << RPB_SHIFT) - 1);
                int hh = n >> 6, dd = n & 63;
                unsigned short* o = (unsigned short*)outp +
                    ((size_t)(bb * H + hh) * D + dd) * KL + ROWOFF + s0;
                short4v pk;
                #pragma unroll
                for (int r = 0; r < 4; ++r) pk[r] = f2b((acc[mi][nj][r] + bi) * scale);
                *reinterpret_cast<short4v*>(o) = pk;
            } else {
                #pragma unroll
                for (int r = 0; r < 4; ++r) {
                    int m = mbase + wr * 64 + mi * 16 + lg * 4 + r;
                    float v = (acc[mi][nj][r] + bi) * scale;
                    if (MODE == 0) {
                        int bb = m >> RPB_SHIFT;
                        int s  = m & ((1 << RPB_SHIFT) - 1);
                        int hh = n >> 6, dd = n & 63;
                        ((unsigned short*)outp)[((size_t)(bb * H + hh) * OUTLEN + ROWOFF + s) * D + dd]
                            = (unsigned short)f2b(v);
                    } else {
                        ((float*)outp)[(size_t)m * DM + n] = v;
                    }
                }
            }
        }
    }
}

// self projections: z=0 Q, z=1 Ks, z=2 Vs (shared A, M=2048)
__global__ __launch_bounds__(256)
void self_proj_kernel(const unsigned short* __restrict__ Abf,
                      const unsigned short* __restrict__ Wq,
                      const unsigned short* __restrict__ Wks,
                      const unsigned short* __restrict__ Wvs,
                      const float* __restrict__ bq,
                      const float* __restrict__ bks,
                      const float* __restrict__ bvs,
                      unsigned short* __restrict__ q_ws,
                      unsigned short* __restrict__ k_ws,
                      unsigned short* __restrict__ vT_ws)
{
    __shared__ unsigned short sA[128 * 32];
    __shared__ unsigned short sB[128 * 32];
    if (blockIdx.z == 0)
        gemm128_body<0, 10, SL, 0>(Abf, Wq,  bq,  q_ws,  0.125f, sA, sB);
    else if (blockIdx.z == 1)
        gemm128_body<0, 10, KL, 0>(Abf, Wks, bks, k_ws,  1.0f,   sA, sB);
    else
        gemm128_body<1, 10, 0,  0>(Abf, Wvs, bvs, vT_ws, 1.0f,   sA, sB);
}

// ctx projections: z=0 Kc, z=1 Vc (shared A, M=1024)
__global__ __launch_bounds__(256)
void ctx_proj_kernel(const unsigned short* __restrict__ Abf,
                     const unsigned short* __restrict__ Wkc,
                     const unsigned short* __restrict__ Wvc,
                     const float* __restrict__ bkc,
                     const float* __restrict__ bvc,
                     unsigned short* __restrict__ k_ws,
                     unsigned short* __restrict__ vT_ws)
{
    __shared__ unsigned short sA[128 * 32];
    __shared__ unsigned short sB[128 * 32];
    if (blockIdx.z == 0)
        gemm128_body<0, 9, KL, SL>(Abf, Wkc, bkc, k_ws,  1.0f, sA, sB);
    else
        gemm128_body<1, 9, 0,  SL>(Abf, Wvc, bvc, vT_ws, 1.0f, sA, sB);
}

// output projection: fp32 out [2048, 1024]
__global__ __launch_bounds__(256)
void out_proj_kernel(const unsigned short* __restrict__ ctx_bf,
                     const unsigned short* __restrict__ Wo,
                     const float* __restrict__ bo,
                     float* __restrict__ out0)
{
    __shared__ unsigned short sA[128 * 32];
    __shared__ unsigned short sB[128 * 32];
    gemm128_body<2, 10, 0, 0>(ctx_bf, Wo, bo, out0, 1.0f, sA, sB);
}

// ---------------- attention: one block per (b,h,16-row q tile) -------------
// 512 threads = 8 waves. LDS ~98.5 KB -> 1 block/CU, 8 waves resident.
__global__ __launch_bounds__(512)
void attn_kernel(const unsigned short* __restrict__ q_ws,
                 const unsigned short* __restrict__ k_ws,
                 const unsigned short* __restrict__ vT_ws,
                 const int* __restrict__ self_mask,
                 const int* __restrict__ ctx_mask,
                 const float* __restrict__ ctx_bias,
                 float* __restrict__ attn_out,
                 float* __restrict__ top_out,
                 unsigned short* __restrict__ ctx_ws)
{
    __shared__ float s_scores[16 * SPAD];   // 98,560 B; PV partials alias this
    __shared__ float s_rden[16];

    const int bid = blockIdx.x;
    const int bh  = bid & 31;        // same head -> same XCD (bid%8 == bh%8)
    const int qt  = bid >> 5;        // 0..63
    const int b   = bh >> 4;
    const int h   = bh & 15;
    const int t   = threadIdx.x;
    const int l   = t & 63;
    const int wid = t >> 6;          // 0..7
    const int lr  = l & 15;
    const int lg  = l >> 4;

    const unsigned short* qb = q_ws + (size_t)bh * SL * D + (size_t)qt * 16 * D;
    const unsigned short* kb = k_ws + (size_t)bh * KL * D;
    const unsigned short* vb = vT_ws + (size_t)bh * D * KL;

    // Q fragments: lane holds Q[l&15][(l>>4)*8 + i], two k-steps of 32
    bf16x8 aq0 = ld8(qb + lr * D + lg * 8);
    bf16x8 aq1 = ld8(qb + lr * D + 32 + lg * 8);

    // scores: 96 col-fragments, 12 per wave
    for (int jj = 0; jj < 12; ++jj) {
        int j  = wid * 12 + jj;
        int kp = j * 16 + lr;
        bf16x8 bk0 = ld8(kb + (size_t)kp * D + lg * 8);
        bf16x8 bk1 = ld8(kb + (size_t)kp * D + 32 + lg * 8);
        f32x4 c = {};
        c = __builtin_amdgcn_mfma_f32_16x16x32_bf16(aq0, bk0, c, 0, 0, 0);
        c = __builtin_amdgcn_mfma_f32_16x16x32_bf16(aq1, bk1, c, 0, 0, 0);
        #pragma unroll
        for (int r = 0; r < 4; ++r)
            s_scores[(lg * 4 + r) * SPAD + j * 16 + lr] = c[r];
    }
    __syncthreads();

    // masked softmax: 32 threads per row, float4-vectorized
    {
        const int rr = t >> 5;           // row 0..15 (two rows per wave)
        const int c0 = t & 31;
        const int qg = qt * 16 + rr;
        const float cb = ctx_bias[0];
        const int4* smrow4 = (const int4*)(self_mask + ((size_t)b * SL + qg) * SL);
        const int4* cmrow4 = (const int4*)(ctx_mask + (size_t)b * CL);
        float* srow = s_scores + rr * SPAD;

        float4 ev[12];
        float mx = -3.0e38f;
        #pragma unroll
        for (int jj = 0; jj < 12; ++jj) {
            int c4 = c0 + jj * 32;       // float4 col, 0..383
            float4 s = *reinterpret_cast<const float4*>(srow + c4 * 4);
            if (c4 < 256) {
                int4 m = smrow4[c4];
                if (m.x) s.x = -1e30f;
                if (m.y) s.y = -1e30f;
                if (m.z) s.z = -1e30f;
                if (m.w) s.w = -1e30f;
            } else {
                int4 m = cmrow4[c4 - 256];
                s.x += cb; s.y += cb; s.z += cb; s.w += cb;
                if (m.x) s.x = -1e30f;
                if (m.y) s.y = -1e30f;
                if (m.z) s.z = -1e30f;
                if (m.w) s.w = -1e30f;
            }
            ev[jj] = s;
            mx = fmaxf(mx, fmaxf(fmaxf(s.x, s.y), fmaxf(s.z, s.w)));
        }
        #pragma unroll
        for (int o = 1; o < 32; o <<= 1) mx = fmaxf(mx, __shfl_xor(mx, o));

        float sum = 0.f, csum = 0.f;
        #pragma unroll
        for (int jj = 0; jj < 12; ++jj) {
            int c4 = c0 + jj * 32;
            float4 s = ev[jj];
            float4 e;
            e.x = __expf(s.x - mx); e.y = __expf(s.y - mx);
            e.z = __expf(s.z - mx); e.w = __expf(s.w - mx);
            ev[jj] = e;
            *reinterpret_cast<float4*>(srow + c4 * 4) = e;
            float se = e.x + e.y + e.z + e.w;
            sum += se;
            if (c4 >= 256) csum += se;
        }
        #pragma unroll
        for (int o = 1; o < 32; o <<= 1) { sum += __shfl_xor(sum, o); csum += __shfl_xor(csum, o); }
        float rden = 1.0f / sum;
        float rcs  = 1.0f / csum;
        if (c0 == 0) s_rden[rr] = rden;

        float4* arow4 = (float4*)(attn_out + ((size_t)bh * SL + qg) * KL);
        float4* trow4 = (float4*)(top_out + ((size_t)b * SL + qg) * CL);
        #pragma unroll
        for (int jj = 0; jj < 12; ++jj) {
            int c4 = c0 + jj * 32;
            float4 e = ev[jj];
            float4 w; w.x = e.x * rden; w.y = e.y * rden; w.z = e.z * rden; w.w = e.w * rden;
            arow4[c4] = w;
            if (h == 0 && c4 >= 256) {
                float4 tw; tw.x = e.x * rcs; tw.y = e.y * rcs; tw.z = e.z * rcs; tw.w = e.w * rcs;
                trow4[c4 - 256] = tw;
            }
        }
    }
    __syncthreads();

    // PV on unnormalized e; wave w owns K slice [w*192, w*192+192)
    f32x4 accv[4] = {};
    for (int ks = 0; ks < 6; ++ks) {
        int k0 = wid * 192 + ks * 32;
        const float* prow = s_scores + lr * SPAD + k0 + lg * 8;
        float4 p0 = *reinterpret_cast<const float4*>(prow);
        float4 p1 = *reinterpret_cast<const float4*>(prow + 4);
        bf16x8 ap;
        ap[0]=f2b(p0.x); ap[1]=f2b(p0.y); ap[2]=f2b(p0.z); ap[3]=f2b(p0.w);
        ap[4]=f2b(p1.x); ap[5]=f2b(p1.y); ap[6]=f2b(p1.z); ap[7]=f2b(p1.w);
        #pragma unroll
        for (int df = 0; df < 4; ++df) {
            bf16x8 bv = ld8(vb + (size_t)(df * 16 + lr) * KL + k0 + lg * 8);
            accv[df] = __builtin_amdgcn_mfma_f32_16x16x32_bf16(ap, bv, accv[df], 0, 0, 0);
        }
    }
    __syncthreads();                   // all PV score-reads done
    float* s_part = s_scores;          // alias: 8 * 1024 floats
    #pragma unroll
    for (int df = 0; df < 4; ++df)
        #pragma unroll
        for (int r = 0; r < 4; ++r)
            s_part[wid * 1024 + (lg * 4 + r) * 64 + df * 16 + lr] = accv[df][r];
    __syncthreads();

    for (int i = t; i < 1024; i += 512) {
        int s = i >> 6, dd = i & 63;
        float v = 0.f;
        #pragma unroll
        for (int w = 0; w < 8; ++w) v += s_part[w * 1024 + i];
        v *= s_rden[s];
        ctx_ws[((size_t)b * SL + (size_t)qt * 16 + s) * DM + h * D + dd] = (unsigned short)f2b(v);
    }
}

extern "C" void kernel_launch(void* const* d_in, const int* in_sizes, int n_in,
                              void* d_out, int out_size, void* d_ws, size_t ws_size,
                              hipStream_t stream)
{
    const float* self_kvq = (const float*)d_in[0];
    const float* ctx_kv   = (const float*)d_in[1];
    const int*   self_mask= (const int*)d_in[2];
    const int*   ctx_mask = (const int*)d_in[3];
    const float* Wq  = (const float*)d_in[4];
    const float* bq  = (const float*)d_in[5];
    const float* Wks = (const float*)d_in[6];
    const float* bks = (const float*)d_in[7];
    const float* Wvs = (const float*)d_in[8];
    const float* bvs = (const float*)d_in[9];
    const float* Wkc = (const float*)d_in[10];
    const float* bkc = (const float*)d_in[11];
    const float* Wvc = (const float*)d_in[12];
    const float* bvc = (const float*)d_in[13];
    const float* ctx_bias = (const float*)d_in[14];
    const float* Wo  = (const float*)d_in[15];
    const float* bo  = (const float*)d_in[16];

    float* out0     = (float*)d_out;                       // (B, SL, DM)
    float* out_top  = out0 + (size_t)B * SL * DM;          // (B, SL, CL)
    float* out_attn = out_top + (size_t)B * SL * CL;       // (B, H, SL, KL)

    unsigned short* wsp  = (unsigned short*)d_ws;
    // conv region, 1M-element units:
    unsigned short* Abf_self = wsp + 0 * M1;   // 2M  (aliased by ctx_ws later)
    unsigned short* Abf_ctx  = wsp + 2 * M1;
    unsigned short* Wq_b     = wsp + 3 * M1;
    unsigned short* Wks_b    = wsp + 4 * M1;
    unsigned short* Wvs_b    = wsp + 5 * M1;
    unsigned short* Wkc_b    = wsp + 6 * M1;
    unsigned short* Wvc_b    = wsp + 7 * M1;
    unsigned short* Wo_b     = wsp + 8 * M1;
    unsigned short* q_ws     = wsp + 9 * M1;   // [B,H,SL,64]   2M
    unsigned short* k_ws     = wsp + 11 * M1;  // [B,H,KL,64]   3M
    unsigned short* vT_ws    = wsp + 14 * M1;  // [B,H,64,KL]   3M
    unsigned short* ctx_ws   = wsp + 0;        // [B*SL, DM]    2M (alias Abf_self)

    ConvSrc cs;
    cs.p[0] = self_kvq; cs.p[1] = ctx_kv;
    cs.p[2] = Wq; cs.p[3] = Wks; cs.p[4] = Wvs;
    cs.p[5] = Wkc; cs.p[6] = Wvc; cs.p[7] = Wo;
    convert_kernel<<<4608, 256, 0, stream>>>(cs, wsp);

    self_proj_kernel<<<dim3(8, 16, 3), 256, 0, stream>>>(
        Abf_self, Wq_b, Wks_b, Wvs_b, bq, bks, bvs, q_ws, k_ws, vT_ws);
    ctx_proj_kernel<<<dim3(8, 8, 2), 256, 0, stream>>>(
        Abf_ctx, Wkc_b, Wvc_b, bkc, bvc, k_ws, vT_ws);

    attn_kernel<<<dim3(2048), 512, 0, stream>>>(q_ws, k_ws, vT_ws,
        self_mask, ctx_mask, ctx_bias, out_attn, out_top, ctx_ws);

    out_proj_kernel<<<dim3(8, 16), 256, 0, stream>>>(ctx_ws, Wo_b, bo, out0);
}